// Round 5
// baseline (413.483 us; speedup 1.0000x reference)
//
#include <hip/hip_runtime.h>

// ---------------------------------------------------------------------------
// MultiheadCosformerAttention: B=4, L=4096, E=1024, H=16, hd=64
// Round 5: k/v stored TRANSPOSED from gemm_qkv epilogue (registers already
//          hold token-dim in rows -> free transpose, packed u32 stores).
//          kv_mfma rebuilt LDS-free: fragments load straight from kT/vT as
//          contiguous 16B per lane; no barriers; grid 16x64.
// ---------------------------------------------------------------------------

typedef unsigned short u16;
typedef unsigned int u32;
typedef __attribute__((ext_vector_type(8))) __bf16 bf16x8;
typedef __attribute__((ext_vector_type(4))) float f32x4;

#define PI_HALF 1.57079632679489662f
#define EPS_Z 1e-4f

__device__ __forceinline__ u16 f32_to_bf16(float f) {
    union { float f; unsigned int u; } x; x.f = f;
    unsigned int lsb = (x.u >> 16) & 1u;
    x.u += 0x7fffu + lsb;                 // round-to-nearest-even
    return (u16)(x.u >> 16);
}
__device__ __forceinline__ float bf16_to_f32(u16 u) {
    union { float f; unsigned int u; } x; x.u = ((unsigned int)u) << 16;
    return x.f;
}

typedef __attribute__((address_space(1))) void amdgpu_global_t;
typedef __attribute__((address_space(3))) void amdgpu_lds_t;
__device__ __forceinline__ void async_load16(const u16* g, u16* l) {
    __builtin_amdgcn_global_load_lds((amdgpu_global_t*)g, (amdgpu_lds_t*)l, 16, 0, 0);
}

// ---------------------------------------------------------------------------
// fp32 -> bf16 converts
// ---------------------------------------------------------------------------
__global__ __launch_bounds__(256) void cvt_bf16(const float* __restrict__ in,
                                                u16* __restrict__ out, int n4) {
    int i = blockIdx.x * 256 + threadIdx.x;
    if (i >= n4) return;
    float4 f = ((const float4*)in)[i];
    ushort4 o;
    o.x = f32_to_bf16(f.x); o.y = f32_to_bf16(f.y);
    o.z = f32_to_bf16(f.z); o.w = f32_to_bf16(f.w);
    ((ushort4*)out)[i] = o;
}

__global__ __launch_bounds__(256) void cvt_w4(const float* __restrict__ w0,
                                              const float* __restrict__ w1,
                                              const float* __restrict__ w2,
                                              const float* __restrict__ w3,
                                              u16* __restrict__ wcat) {
    const float* src = (blockIdx.y == 0) ? w0 : (blockIdx.y == 1) ? w1
                     : (blockIdx.y == 2) ? w2 : w3;
    u16* dst = wcat + (size_t)blockIdx.y * 1048576;
    int i = blockIdx.x * 256 + threadIdx.x;
    float4 f = ((const float4*)src)[i];
    ushort4 o;
    o.x = f32_to_bf16(f.x); o.y = f32_to_bf16(f.y);
    o.z = f32_to_bf16(f.z); o.w = f32_to_bf16(f.w);
    ((ushort4*)dst)[i] = o;
}

// ---------------------------------------------------------------------------
// Fused QKV GEMM (m97 structure). Wcat = [3072][1024] (Wq;Wk;Wv).
// q written row-major [token][feat]; k,v written TRANSPOSED [feat][token]
// (packed 2xbf16 u32 stores; token rows are the register r-dim -> free).
// ---------------------------------------------------------------------------
__global__ __launch_bounds__(256) void gemm_qkv(const u16* __restrict__ A,
                                                const u16* __restrict__ Wcat,
                                                const float* __restrict__ bq,
                                                const float* __restrict__ bk,
                                                const float* __restrict__ bv,
                                                u16* __restrict__ qo,
                                                u16* __restrict__ kTo,
                                                u16* __restrict__ vTo) {
    __shared__ u16 As[128 * 32];
    __shared__ u16 Bs[128 * 32];
    const int K = 1024;
    const int tid  = threadIdx.x;
    const int wave = tid >> 6;
    const int lane = tid & 63;
    const int quad = lane >> 4;
    const int l15  = lane & 15;
    const long tileM = (long)blockIdx.x * 128;
    const long tileN = (long)blockIdx.y * 128;
    const int mat = blockIdx.y >> 3;
    const float* bias = (mat == 0) ? bq : (mat == 1) ? bk : bv;
    const int wm = (wave >> 1) * 64;
    const int wn = (wave & 1) * 64;
    const int s_row = wave * 32 + (lane >> 2);
    const int s_col = (lane & 3) * 8;

    const u16* gA = A    + (tileM + s_row) * (long)K + s_col;
    const u16* gB = Wcat + (tileN + s_row) * (long)K + s_col;
    u16* lA = &As[wave * 1024];
    u16* lB = &Bs[wave * 1024];

    f32x4 acc[4][4] = {};

    for (int kb = 0; kb < K; kb += 32) {
        async_load16(gA,                lA);
        async_load16(gA + 16 * (long)K, lA + 512);
        async_load16(gB,                lB);
        async_load16(gB + 16 * (long)K, lB + 512);
        gA += 32; gB += 32;
        __syncthreads();
        bf16x8 af[4], bf[4];
#pragma unroll
        for (int i = 0; i < 4; i++) {
            af[i] = *(const bf16x8*)&As[(wm + i * 16 + l15) * 32 + quad * 8];
            bf[i] = *(const bf16x8*)&Bs[(wn + i * 16 + l15) * 32 + quad * 8];
        }
#pragma unroll
        for (int i = 0; i < 4; i++)
#pragma unroll
            for (int j = 0; j < 4; j++)
                acc[i][j] = __builtin_amdgcn_mfma_f32_16x16x32_bf16(
                    af[i], bf[j], acc[i][j], 0, 0, 0);
        __syncthreads();
    }

    if (mat == 0) {
        // q: row-major, relu
#pragma unroll
        for (int j = 0; j < 4; j++) {
            const int nl = (int)(tileN + wn + j * 16 + l15) & 1023;
            const float bv_ = bias[nl];
#pragma unroll
            for (int i = 0; i < 4; i++) {
                const long m0 = tileM + wm + i * 16 + quad * 4;
#pragma unroll
                for (int r = 0; r < 4; r++) {
                    float v = fmaxf(acc[i][j][r] + bv_, 0.0f);
                    qo[(m0 + r) * 1024 + nl] = f32_to_bf16(v);
                }
            }
        }
    } else {
        // k (relu) / v: transposed [feat][token], packed u32 stores
        u16* outT = (mat == 1) ? kTo : vTo;
        const bool relu = (mat == 1);
#pragma unroll
        for (int j = 0; j < 4; j++) {
            const int nl = (int)(tileN + wn + j * 16 + l15) & 1023;
            const float bv_ = bias[nl];
#pragma unroll
            for (int i = 0; i < 4; i++) {
                const long m0 = tileM + wm + i * 16 + quad * 4;
                float v0 = acc[i][j][0] + bv_;
                float v1 = acc[i][j][1] + bv_;
                float v2 = acc[i][j][2] + bv_;
                float v3 = acc[i][j][3] + bv_;
                if (relu) {
                    v0 = fmaxf(v0, 0.0f); v1 = fmaxf(v1, 0.0f);
                    v2 = fmaxf(v2, 0.0f); v3 = fmaxf(v3, 0.0f);
                }
                u32 p0 = (u32)f32_to_bf16(v0) | ((u32)f32_to_bf16(v1) << 16);
                u32 p1 = (u32)f32_to_bf16(v2) | ((u32)f32_to_bf16(v3) << 16);
                u32* dst = (u32*)(outT + (size_t)nl * 16384 + m0);
                dst[0] = p0; dst[1] = p1;
            }
        }
    }
}

// ---------------------------------------------------------------------------
// Output-projection GEMM (fp32 out), m97 structure.
// ---------------------------------------------------------------------------
__global__ __launch_bounds__(256) void gemm_o(const u16* __restrict__ A,
                                              const u16* __restrict__ Bw,
                                              const float* __restrict__ bias,
                                              float* __restrict__ Cout,
                                              int M, int N, int K) {
    __shared__ u16 As[128 * 32];
    __shared__ u16 Bs[128 * 32];
    const int tid  = threadIdx.x;
    const int wave = tid >> 6;
    const int lane = tid & 63;
    const int quad = lane >> 4;
    const int l15  = lane & 15;
    const long tileM = (long)blockIdx.x * 128;
    const long tileN = (long)blockIdx.y * 128;
    const int wm = (wave >> 1) * 64;
    const int wn = (wave & 1) * 64;
    const int s_row = wave * 32 + (lane >> 2);
    const int s_col = (lane & 3) * 8;

    const u16* gA = A  + (tileM + s_row) * (long)K + s_col;
    const u16* gB = Bw + (tileN + s_row) * (long)K + s_col;
    u16* lA = &As[wave * 1024];
    u16* lB = &Bs[wave * 1024];

    f32x4 acc[4][4] = {};

    for (int kb = 0; kb < K; kb += 32) {
        async_load16(gA,                lA);
        async_load16(gA + 16 * (long)K, lA + 512);
        async_load16(gB,                lB);
        async_load16(gB + 16 * (long)K, lB + 512);
        gA += 32; gB += 32;
        __syncthreads();
        bf16x8 af[4], bf[4];
#pragma unroll
        for (int i = 0; i < 4; i++) {
            af[i] = *(const bf16x8*)&As[(wm + i * 16 + l15) * 32 + quad * 8];
            bf[i] = *(const bf16x8*)&Bs[(wn + i * 16 + l15) * 32 + quad * 8];
        }
#pragma unroll
        for (int i = 0; i < 4; i++)
#pragma unroll
            for (int j = 0; j < 4; j++)
                acc[i][j] = __builtin_amdgcn_mfma_f32_16x16x32_bf16(
                    af[i], bf[j], acc[i][j], 0, 0, 0);
        __syncthreads();
    }

#pragma unroll
    for (int j = 0; j < 4; j++) {
        const long n = tileN + wn + j * 16 + l15;
        const float bv = bias[n];
#pragma unroll
        for (int i = 0; i < 4; i++) {
            const long m0 = tileM + wm + i * 16 + quad * 4;
#pragma unroll
            for (int r = 0; r < 4; r++)
                Cout[(m0 + r) * (long)N + n] = acc[i][j][r] + bv;
        }
    }
}

// ---------------------------------------------------------------------------
// Stage C (MFMA, LDS-free): per (chunk, head):
//   part[d2=128][n=80] += k_^T @ [v | 1 | 0] over 256 l's.
// Fragments load directly from kT/vT ([feat][token]): per-lane contiguous 16B.
// No LDS, no barriers. grid (16, 64), 4 waves: wave w covers m=[w*32,w*32+32),
// scale = (w>=2 ? cos : sin). part: [chunk16][head64][128][80] bf16.
// ---------------------------------------------------------------------------
__global__ __launch_bounds__(256) void kv_mfma(const u16* __restrict__ kT,
                                               const u16* __restrict__ vT,
                                               u16* __restrict__ part) {
    const int tid = threadIdx.x;
    const int wave = tid >> 6, lane = tid & 63;
    const int quad = lane >> 4, l15 = lane & 15;
    const int head = blockIdx.y;
    const int b = head >> 4, h = head & 15;
    const long col0 = (long)b * 4096 + blockIdx.x * 256 + quad * 8;
    const bool use_cos = (wave >> 1) != 0;
    const int mbase = wave * 32;

    const u16* ka[2];
#pragma unroll
    for (int i = 0; i < 2; i++) {
        const int d = (mbase + i * 16 + l15) & 63;
        ka[i] = kT + (size_t)(h * 64 + d) * 16384 + col0;
    }
    const u16* va[4];
#pragma unroll
    for (int j = 0; j < 4; j++) {
        const int n = j * 16 + l15;
        va[j] = vT + (size_t)(h * 64 + n) * 16384 + col0;
    }

    // angles for l = blockIdx.x*256 + kt*32 + quad*8 + e; rotated per tile
    float sv[8], cv[8];
#pragma unroll
    for (int e = 0; e < 8; e++) {
        float ang = (PI_HALF / 4096.0f) * (float)(blockIdx.x * 256 + quad * 8 + e + 1);
        sv[e] = sinf(ang); cv[e] = cosf(ang);
    }
    const float cD = 0.9999247018391445f;   // cos(pi/256)
    const float sD = 0.0122715382857199f;   // sin(pi/256)

    bf16x8 onesf;
#pragma unroll
    for (int e = 0; e < 8; e++)
        onesf[e] = (l15 == 0) ? (__bf16)1.0f : (__bf16)0.0f;

    f32x4 acc[2][5] = {};

    for (int kt = 0; kt < 8; kt++) {
        bf16x8 kraw[2], bfr[5];
#pragma unroll
        for (int i = 0; i < 2; i++) kraw[i] = *(const bf16x8*)(ka[i] + kt * 32);
#pragma unroll
        for (int j = 0; j < 4; j++) bfr[j] = *(const bf16x8*)(va[j] + kt * 32);
        bfr[4] = onesf;
        bf16x8 af[2];
#pragma unroll
        for (int i = 0; i < 2; i++)
#pragma unroll
            for (int e = 0; e < 8; e++)
                af[i][e] = (__bf16)((float)kraw[i][e] * (use_cos ? cv[e] : sv[e]));
#pragma unroll
        for (int i = 0; i < 2; i++)
#pragma unroll
            for (int j = 0; j < 5; j++)
                acc[i][j] = __builtin_amdgcn_mfma_f32_16x16x32_bf16(
                    af[i], bfr[j], acc[i][j], 0, 0, 0);
#pragma unroll
        for (int e = 0; e < 8; e++) {
            const float ns = sv[e] * cD + cv[e] * sD;
            cv[e] = cv[e] * cD - sv[e] * sD;
            sv[e] = ns;
        }
    }

    u16* op = part + ((size_t)blockIdx.x * 64 + head) * 10240;
#pragma unroll
    for (int i = 0; i < 2; i++)
#pragma unroll
        for (int j = 0; j < 5; j++)
#pragma unroll
            for (int r = 0; r < 4; r++)
                op[(mbase + i * 16 + quad * 4 + r) * 80 + j * 16 + l15] =
                    f32_to_bf16(acc[i][j][r]);
}

// ---------------------------------------------------------------------------
// Stage C2: sum 16 bf16 chunk-partials, transpose to Bt[head][n=80][d2=128].
// grid (4 d2-tiles of 32, 64 heads), 256 threads.
// ---------------------------------------------------------------------------
__global__ __launch_bounds__(256) void kv_reduce_t(const u16* __restrict__ part,
                                                   u16* __restrict__ Bt) {
    __shared__ float accs[32 * 81];
    const int head = blockIdx.y, d2t = blockIdx.x;
    const u16* bp = part + (size_t)head * 10240 + d2t * 32 * 80;
    for (int idx = threadIdx.x; idx < 2560; idx += 256) {
        float s = 0.0f;
#pragma unroll
        for (int c = 0; c < 16; c++)
            s += bf16_to_f32(bp[(size_t)c * 655360 + idx]);
        const int d2 = idx / 80, n = idx - d2 * 80;
        accs[d2 * 81 + n] = s;
    }
    __syncthreads();
    for (int idx = threadIdx.x; idx < 2560; idx += 256) {
        const int n = idx >> 5, d2 = idx & 31;
        Bt[(size_t)head * 10240 + n * 128 + d2t * 32 + d2] =
            f32_to_bf16(accs[d2 * 81 + n]);
    }
}

// ---------------------------------------------------------------------------
// Stage D: per-head MFMA GEMM: attn[l, 0..79] = q_[l, 0..127] @ Bt^T
// ---------------------------------------------------------------------------
__global__ __launch_bounds__(256) void attn_mfma(const u16* __restrict__ qb,
                                                 const u16* __restrict__ Bt,
                                                 u16* __restrict__ merged) {
    __shared__ __align__(16) u16 As[128 * 72];   // q tile [l][64], stride 72
    __shared__ __align__(16) u16 Bs[80 * 136];   // Bt tile [n][128], stride 136
    const int tid = threadIdx.x;
    const int wave = tid >> 6, lane = tid & 63;
    const int quad = lane >> 4, l15 = lane & 15;
    const int head = blockIdx.y;
    const int b = head >> 4, h = head & 15;
    const int tm = blockIdx.x * 128;
    const long b4 = (long)b * 4096;

    for (int c = tid; c < 1024; c += 256) {
        const int row = c >> 3, c8 = c & 7;
        uint4 t = *(const uint4*)(qb + (b4 + tm + row) * 1024 + h * 64 + c8 * 8);
        *(uint4*)&As[row * 72 + c8 * 8] = t;
    }
    for (int c = tid; c < 1280; c += 256) {
        const int row = c >> 4, c16 = c & 15;
        uint4 t = *(const uint4*)(Bt + (long)head * 10240 + row * 128 + c16 * 8);
        *(uint4*)&Bs[row * 136 + c16 * 8] = t;
    }
    const int wm = wave * 32;
    float snl[2], csl[2];
#pragma unroll
    for (int i = 0; i < 2; i++) {
        const int l = tm + wm + i * 16 + l15;
        const float idx = PI_HALF * (float)(l + 1) * (1.0f / 4096.0f);
        snl[i] = sinf(idx); csl[i] = cosf(idx);
    }
    __syncthreads();

    f32x4 acc[2][5] = {};
#pragma unroll
    for (int kb = 0; kb < 4; kb++) {
        const int qc = (kb & 1) * 32 + quad * 8;
        bf16x8 af[2];
#pragma unroll
        for (int i = 0; i < 2; i++) {
            bf16x8 raw = *(const bf16x8*)&As[(wm + i * 16 + l15) * 72 + qc];
            const float s = (kb < 2) ? snl[i] : csl[i];
            bf16x8 sc;
#pragma unroll
            for (int e = 0; e < 8; e++) sc[e] = (__bf16)((float)raw[e] * s);
            af[i] = sc;
        }
        bf16x8 bf[5];
#pragma unroll
        for (int j = 0; j < 5; j++)
            bf[j] = *(const bf16x8*)&Bs[(j * 16 + l15) * 136 + kb * 32 + quad * 8];
#pragma unroll
        for (int i = 0; i < 2; i++)
#pragma unroll
            for (int j = 0; j < 5; j++)
                acc[i][j] = __builtin_amdgcn_mfma_f32_16x16x32_bf16(
                    af[i], bf[j], acc[i][j], 0, 0, 0);
    }

#pragma unroll
    for (int i = 0; i < 2; i++) {
        float z[4];
#pragma unroll
        for (int r = 0; r < 4; r++) {
            const float den = __shfl(acc[i][4][r], lane & 0x30, 64);
            z[r] = 1.0f / fmaxf(den, EPS_Z);
        }
#pragma unroll
        for (int j = 0; j < 4; j++)
#pragma unroll
            for (int r = 0; r < 4; r++) {
                const int l = tm + wm + i * 16 + quad * 4 + r;
                merged[(b4 + l) * 1024 + h * 64 + j * 16 + l15] =
                    f32_to_bf16(acc[i][j][r] * z[r]);
            }
    }
}

// ---------------------------------------------------------------------------
extern "C" void kernel_launch(void* const* d_in, const int* in_sizes, int n_in,
                              void* d_out, int out_size, void* d_ws, size_t ws_size,
                              hipStream_t stream) {
    (void)in_sizes; (void)n_in; (void)out_size; (void)ws_size;
    const float* x  = (const float*)d_in[0];
    const float* Wq = (const float*)d_in[1];
    const float* bq = (const float*)d_in[2];
    const float* Wk = (const float*)d_in[3];
    const float* bk = (const float*)d_in[4];
    const float* Wv = (const float*)d_in[5];
    const float* bv = (const float*)d_in[6];
    const float* Wo = (const float*)d_in[7];
    const float* bo = (const float*)d_in[8];
    float* out = (float*)d_out;

    const int M = 16384, E = 1024;
    char* ws = (char*)d_ws;
    const size_t MB = 1048576;
    u16* xb   = (u16*)(ws);              // 32 MiB; dead after QKV GEMM -> part
    u16* qb   = (u16*)(ws + 32 * MB);
    u16* kTb  = (u16*)(ws + 64 * MB);    // [1024][16384] bf16; dead after kv_mfma
    u16* vTb  = (u16*)(ws + 96 * MB);    // [1024][16384] bf16; dead after kv_mfma
    u16* wcat = (u16*)(ws + 128 * MB);   // Wq;Wk;Wv;Wo bf16, 8 MiB
    u16* wob  = wcat + 3 * (size_t)E * E;
    u16* Btb  = (u16*)(ws + 136 * MB);   // 1.25 MiB
    u16* partb = xb;                     // 16*64*10240 bf16 = 20 MiB
    u16* mergedb = kTb;                  // reuse dead kT region

    cvt_bf16<<<dim3(M * E / 4 / 256), dim3(256), 0, stream>>>(x, xb, M * E / 4);
    cvt_w4<<<dim3(E * E / 4 / 256, 4), dim3(256), 0, stream>>>(Wq, Wk, Wv, Wo, wcat);

    gemm_qkv<<<dim3(M / 128, 24), dim3(256), 0, stream>>>(xb, wcat, bq, bk, bv,
                                                          qb, kTb, vTb);

    kv_mfma<<<dim3(16, 64), dim3(256), 0, stream>>>(kTb, vTb, partb);
    kv_reduce_t<<<dim3(4, 64), dim3(256), 0, stream>>>(partb, Btb);
    attn_mfma<<<dim3(32, 64), dim3(256), 0, stream>>>(qb, Btb, mergedb);

    gemm_o<<<dim3(M / 128, E / 128), dim3(256), 0, stream>>>(mergedb, wob, bo,
                                                             out, M, E, E);
}